// Round 6
// baseline (1076.933 us; speedup 1.0000x reference)
//
#include <hip/hip_runtime.h>
#include <hip/hip_bf16.h>
#include <math.h>

// Problem constants
#define BB 32
#define TT 12
#define NN 512
#define HH 64
#define KK 3
#define DIN 65
#define BD 2080        // BB*DIN valid cols
#define BDP 2176       // padded cols = 17*128
#define ROWS 1536      // KK*NN
#define NSUB 136       // BDP/16
#define MSUB 96        // ROWS/16
#define RTOT 16384     // BB*NN dense rows
#define KP 224         // dense K padded (195 -> 7*32)

typedef _Float16 f16;
typedef f16 f16x8 __attribute__((ext_vector_type(8)));
typedef float f32x4 __attribute__((ext_vector_type(4)));

#define GLD_LDS16(g, l) \
    __builtin_amdgcn_global_load_lds((const __attribute__((address_space(1))) void*)(g), \
                                     (__attribute__((address_space(3))) void*)(l), 16, 0, 0)

// Bf fragment address for element (node j, col c), in f16 units
__device__ __forceinline__ int bf_addr(int j, int c) {
    return (((j >> 5) * NSUB + (c >> 4)) * 64 + ((j >> 3) & 3) * 16 + (c & 15)) * 8 + (j & 7);
}

// ---------------- convert P (f32, 1536x512 row-major) -> fragment-major f16 A ----------------
__global__ __launch_bounds__(256) void conv_a(const float* __restrict__ P, f16* __restrict__ Af) {
    int u = blockIdx.x * 256 + threadIdx.x;  // 1536*512/8 slots
    int lane = u & 63;
    int su = u >> 6;
    int ks = su / MSUB, ms = su - ks * MSUB;
    int m = ms * 16 + (lane & 15);
    int k = ks * 32 + (lane >> 4) * 8;
    const float* src = &P[(size_t)m * 512 + k];
    f16x8 v;
#pragma unroll
    for (int i = 0; i < 8; ++i) v[i] = (f16)src[i];
    *(f16x8*)&Af[(size_t)u * 8] = v;
}

// ---------------- convert dense weight (195 x O f32) -> fragment-major f16, K padded to 224 ----
__global__ __launch_bounds__(256) void conv_w(const float* __restrict__ W, int O, int OS,
                                              f16* __restrict__ Wf) {
    int u = blockIdx.x * 256 + threadIdx.x;
    if (u >= 7 * OS * 64) return;
    int lane = u & 63;
    int su = u >> 6;
    int ks = su / OS, os = su - ks * OS;
    int o = os * 16 + (lane & 15);
    int k0 = ks * 32 + (lane >> 4) * 8;
    f16x8 v;
#pragma unroll
    for (int i = 0; i < 8; ++i) {
        int kk = k0 + i;
        v[i] = (kk < 195) ? (f16)W[kk * O + o] : (f16)0.f;
    }
    *(f16x8*)&Wf[(size_t)u * 8] = v;
}

// ---------------- update Bf x-columns (p=0): from x[b,0,:,0] (prologue only) -----------------
__global__ __launch_bounds__(256) void upd_x(const float* __restrict__ x, int t,
                                             f16* __restrict__ Bf) {
    int idx = blockIdx.x * 256 + threadIdx.x;  // R = b*512+n
    if (idx >= RTOT) return;
    int b = idx >> 9, n = idx & 511;
    float v = x[((size_t)b * TT + t) * NN + n];
    Bf[bf_addr(n, b * DIN)] = (f16)v;
}

// ---------------- big MFMA GEMM: S_t = (Af @ Bf) stored as f16 [(b,n)][k*65+p], stride 256 ----
// Block = 192 A-rows (all 3 k-layers x 64-node band) x 128 cols; BK=64; grid (17, 8) = 136.
// 4 waves; wave owns 48 rows (3 msubs) x 128 cols (8 nsubs) = 48 MFMA per K64-step.
// LDS per buf: 24 A-subtiles + 16 B-subtiles = 40 x 512 f16 = 40 KB; double-buffered = 80 KB.
__global__ __launch_bounds__(256, 1) void mm_f16(const f16* __restrict__ Af,
                                                 const f16* __restrict__ Bf,
                                                 f16* __restrict__ St) {
    __shared__ f16 lds[2][20480];
    int tid = threadIdx.x, wave = tid >> 6, lane = tid & 63;
    int nb = blockIdx.x, mb = blockIdx.y;
    f32x4 acc[3][8] = {};

#define STG(d, it)                                                                               \
    do {                                                                                         \
        _Pragma("unroll") for (int q10 = 0; q10 < 10; ++q10) {                                   \
            int q = q10 * 4 + wave;                                                              \
            if (q < 24) {                                                                        \
                int ksl = q / 12, aid = q % 12;                                                  \
                int ms = (aid >> 2) * 32 + mb * 4 + (aid & 3);                                   \
                GLD_LDS16(&Af[((size_t)(((it)*2 + ksl) * MSUB + ms) * 64 + lane) * 8],           \
                          &lds[d][q * 512 + lane * 8]);                                          \
            } else {                                                                             \
                int qb = q - 24, ksl = qb >> 3, nsb = qb & 7;                                    \
                GLD_LDS16(&Bf[((size_t)(((it)*2 + ksl) * NSUB + nb * 8 + nsb) * 64 + lane) * 8], \
                          &lds[d][q * 512 + lane * 8]);                                          \
            }                                                                                    \
        }                                                                                        \
    } while (0)

    STG(0, 0);
#pragma unroll 1
    for (int it = 0; it < 8; ++it) {
        int d = it & 1;
        __syncthreads();
        if (it + 1 < 8) STG(d ^ 1, it + 1);
#pragma unroll
        for (int kk = 0; kk < 2; ++kk) {
            f16x8 a[3], b[8];
#pragma unroll
            for (int i = 0; i < 3; ++i)
                a[i] = *(const f16x8*)&lds[d][(kk * 12 + 3 * wave + i) * 512 + lane * 8];
#pragma unroll
            for (int j = 0; j < 8; ++j)
                b[j] = *(const f16x8*)&lds[d][(24 + kk * 8 + j) * 512 + lane * 8];
#pragma unroll
            for (int i = 0; i < 3; ++i)
#pragma unroll
                for (int j = 0; j < 8; ++j)
                    acc[i][j] = __builtin_amdgcn_mfma_f32_16x16x32_f16(a[i], b[j], acc[i][j], 0, 0, 0);
        }
    }
#undef STG

    // epilogue: frag (aid=3*wave+i, nsub j) -> St[(b*512+n)*256 + k*65+p]
    int col = lane & 15;
#pragma unroll
    for (int i = 0; i < 3; ++i) {
        int aid = 3 * wave + i;
        int k = aid >> 2;
        int nr0 = mb * 64 + (aid & 3) * 16 + (lane >> 4) * 4;
#pragma unroll
        for (int j = 0; j < 8; ++j) {
            int c = nb * 128 + j * 16 + col;
            if (c < BD) {
                int b = c / DIN, p = c - b * DIN;
                size_t base = ((size_t)b * 512 + nr0) * 256 + k * DIN + p;
#pragma unroll
                for (int rI = 0; rI < 4; ++rI)
                    St[base + (size_t)rI * 256] = (f16)acc[i][j][rI];
            }
        }
    }
}

// ---------------- gates dense: zr = sigmoid(S_t @ Wg + bg); z->zf frags, r*h -> Bf ------------
// M=16384, N=128, K=224. Block: 64 rows, 4 waves 2x2, wave = 32R x 64o.
__global__ __launch_bounds__(256) void dense_gates(const f16* __restrict__ St,
                                                   const f16* __restrict__ Wf,
                                                   const float* __restrict__ bias,
                                                   const float* __restrict__ hf,
                                                   float* __restrict__ zf,
                                                   f16* __restrict__ Bf) {
    int tid = threadIdx.x, wave = tid >> 6, lane = tid & 63;
    int wr = wave & 1, wc = wave >> 1;
    int R0 = blockIdx.x * 64 + wr * 32;

    f16x8 af[7][2];
    const f16* Sb = St + (size_t)(R0 + (lane & 15)) * 256 + (lane >> 4) * 8;
#pragma unroll
    for (int ks = 0; ks < 7; ++ks)
#pragma unroll
        for (int rs = 0; rs < 2; ++rs)
            af[ks][rs] = *(const f16x8*)&Sb[(size_t)rs * 16 * 256 + ks * 32];

    f32x4 acc[2][4] = {};
#pragma unroll
    for (int ks = 0; ks < 7; ++ks)
#pragma unroll
        for (int os = 0; os < 4; ++os) {
            f16x8 w = *(const f16x8*)&Wf[((size_t)(ks * 8 + wc * 4 + os) * 64 + lane) * 8];
#pragma unroll
            for (int rs = 0; rs < 2; ++rs)
                acc[rs][os] = __builtin_amdgcn_mfma_f32_16x16x32_f16(af[ks][rs], w, acc[rs][os], 0, 0, 0);
        }

    int col = lane & 15;
#pragma unroll
    for (int rs = 0; rs < 2; ++rs) {
        int rf = (R0 >> 4) + rs;
#pragma unroll
        for (int os = 0; os < 4; ++os) {
            int o = wc * 64 + os * 16 + col;
            float bs = bias[o];
            if (wc == 0) {
                f32x4 v;
#pragma unroll
                for (int rI = 0; rI < 4; ++rI) v[rI] = 1.f / (1.f + expf(-(acc[rs][os][rI] + bs)));
                *(f32x4*)&zf[((size_t)(rf * 4 + os) * 64 + lane) * 4] = v;
            } else {
                int oh = o - 64;
                f32x4 hv = *(const f32x4*)&hf[((size_t)(rf * 4 + os) * 64 + lane) * 4];
#pragma unroll
                for (int rI = 0; rI < 4; ++rI) {
                    float rr = 1.f / (1.f + expf(-(acc[rs][os][rI] + bs)));
                    int R = rf * 16 + (lane >> 4) * 4 + rI;
                    int n = R & 511, b = R >> 9;
                    Bf[bf_addr(n, b * DIN + 1 + oh)] = (f16)(rr * hv[rI]);
                }
            }
        }
    }
}

// ------- candidate dense + GRU update + fused tail (encoder: next-x write; decoder: proj) -----
// h = (1-z)h + z*tanh(S_t @ Wu + bu). Block: 64 rows, 4 waves 2x2, wave = 32R x 32o.
// mode 0 (encoder): tail writes Bf x-col = xnext[b,tnext,n] (or 0 if xnext==null).
// mode 1 (decoder): tail computes go = h @ Wp + bp, writes out[b,t,n] and Bf x-col.
__global__ __launch_bounds__(256) void dense_cand(const f16* __restrict__ St,
                                                  const f16* __restrict__ Wf,
                                                  const float* __restrict__ bias,
                                                  const float* __restrict__ zf,
                                                  float* __restrict__ hf,
                                                  f16* __restrict__ Bf,
                                                  const float* __restrict__ xnext, int tnext,
                                                  const float* __restrict__ Wp,
                                                  const float* __restrict__ bp,
                                                  float* __restrict__ outp, int t, int hor,
                                                  int mode) {
    __shared__ float pls[2][64][16];  // [wc][row-in-block][col-lane] proj partials
    int tid = threadIdx.x, wave = tid >> 6, lane = tid & 63;
    int wr = wave & 1, wc = wave >> 1;
    int R0 = blockIdx.x * 64 + wr * 32;

    f16x8 af[7][2];
    const f16* Sb = St + (size_t)(R0 + (lane & 15)) * 256 + (lane >> 4) * 8;
#pragma unroll
    for (int ks = 0; ks < 7; ++ks)
#pragma unroll
        for (int rs = 0; rs < 2; ++rs)
            af[ks][rs] = *(const f16x8*)&Sb[(size_t)rs * 16 * 256 + ks * 32];

    f32x4 acc[2][2] = {};
#pragma unroll
    for (int ks = 0; ks < 7; ++ks)
#pragma unroll
        for (int os = 0; os < 2; ++os) {
            f16x8 w = *(const f16x8*)&Wf[((size_t)(ks * 4 + wc * 2 + os) * 64 + lane) * 8];
#pragma unroll
            for (int rs = 0; rs < 2; ++rs)
                acc[rs][os] = __builtin_amdgcn_mfma_f32_16x16x32_f16(af[ks][rs], w, acc[rs][os], 0, 0, 0);
        }

    int col = lane & 15;
    float pp[2][4] = {};  // [rs][rI] proj partial over this wave's o columns
#pragma unroll
    for (int rs = 0; rs < 2; ++rs) {
        int rf = (R0 >> 4) + rs;
#pragma unroll
        for (int os = 0; os < 2; ++os) {
            int o = wc * 32 + os * 16 + col;
            int of = wc * 2 + os;
            float bs = bias[o];
            float wp = (mode == 1) ? Wp[o] : 0.f;
            f32x4 zv = *(const f32x4*)&zf[((size_t)(rf * 4 + of) * 64 + lane) * 4];
            f32x4 hv = *(const f32x4*)&hf[((size_t)(rf * 4 + of) * 64 + lane) * 4];
            f32x4 hn;
#pragma unroll
            for (int rI = 0; rI < 4; ++rI) {
                float hc = tanhf(acc[rs][os][rI] + bs);
                hn[rI] = (1.f - zv[rI]) * hv[rI] + zv[rI] * hc;
                pp[rs][rI] += hn[rI] * wp;
            }
            *(f32x4*)&hf[((size_t)(rf * 4 + of) * 64 + lane) * 4] = hn;
#pragma unroll
            for (int rI = 0; rI < 4; ++rI) {
                int R = rf * 16 + (lane >> 4) * 4 + rI;
                int n = R & 511, b = R >> 9;
                Bf[bf_addr(n, b * DIN + 1 + o)] = (f16)hn[rI];
            }
        }
    }
    if (mode == 1) {
#pragma unroll
        for (int rs = 0; rs < 2; ++rs)
#pragma unroll
            for (int rI = 0; rI < 4; ++rI)
                pls[wc][wr * 32 + rs * 16 + (lane >> 4) * 4 + rI][col] = pp[rs][rI];
    }
    __syncthreads();
    if (tid < 64) {
        int rb = tid;
        int R = blockIdx.x * 64 + rb;
        int n = R & 511, b = R >> 9;
        if (mode == 1) {
            float v = bp[0];
#pragma unroll
            for (int cc = 0; cc < 16; ++cc) v += pls[0][rb][cc] + pls[1][rb][cc];
            outp[((size_t)b * hor + t) * NN + n] = v;
            Bf[bf_addr(n, b * DIN)] = (f16)v;
        } else {
            float v = xnext ? xnext[((size_t)b * TT + tnext) * NN + n] : 0.f;
            Bf[bf_addr(n, b * DIN)] = (f16)v;
        }
    }
}

extern "C" void kernel_launch(void* const* d_in, const int* in_sizes, int n_in,
                              void* d_out, int out_size, void* d_ws, size_t ws_size,
                              hipStream_t stream) {
    const float* x   = (const float*)d_in[0];
    const float* P   = (const float*)d_in[1];
    const float* Weg = (const float*)d_in[2];
    const float* beg = (const float*)d_in[3];
    const float* Weu = (const float*)d_in[4];
    const float* beu = (const float*)d_in[5];
    const float* Wdg = (const float*)d_in[6];
    const float* bdg = (const float*)d_in[7];
    const float* Wdu = (const float*)d_in[8];
    const float* bdu = (const float*)d_in[9];
    const float* Wp  = (const float*)d_in[10];
    const float* bp  = (const float*)d_in[11];
    float* out = (float*)d_out;
    int hor = out_size / (BB * NN);

    float* ws = (float*)d_ws;
    size_t off = 0;
    float* hf = ws + off; off += (size_t)RTOT * HH;                 // frag-major h (4 MB)
    float* zf = ws + off; off += (size_t)RTOT * HH;                 // frag-major z (4 MB)
    f16* St   = (f16*)(ws + off); off += (size_t)RTOT * 256 / 2;    // S_t f16 [16384][256]
    f16* Bf   = (f16*)(ws + off); off += (size_t)512 * BDP / 2;     // B frag-major
    f16* Af   = (f16*)(ws + off); off += (size_t)ROWS * 512 / 2;    // A frag-major
    f16* Wfeg = (f16*)(ws + off); off += 7 * 8 * 64 * 8 / 2;
    f16* Wfeu = (f16*)(ws + off); off += 7 * 4 * 64 * 8 / 2;
    f16* Wfdg = (f16*)(ws + off); off += 7 * 8 * 64 * 8 / 2;
    f16* Wfdu = (f16*)(ws + off); off += 7 * 4 * 64 * 8 / 2;

    hipMemsetAsync(hf, 0, (size_t)RTOT * HH * sizeof(float), stream);
    hipMemsetAsync(Bf, 0, (size_t)512 * BDP * sizeof(f16), stream);
    hipMemsetAsync(St, 0, (size_t)RTOT * 256 * sizeof(f16), stream);  // k-pad cols must be finite

    conv_a<<<(ROWS * 512 / 8) / 256, 256, 0, stream>>>(P, Af);
    conv_w<<<14, 256, 0, stream>>>(Weg, 128, 8, Wfeg);
    conv_w<<<7,  256, 0, stream>>>(Weu, 64, 4, Wfeu);
    conv_w<<<14, 256, 0, stream>>>(Wdg, 128, 8, Wfdg);
    conv_w<<<7,  256, 0, stream>>>(Wdu, 64, 4, Wfdu);
    upd_x<<<RTOT / 256, 256, 0, stream>>>(x, 0, Bf);

    dim3 mmgrid(BDP / 128, 8);  // 17 x 8 = 136 blocks, each does all 3 k-layers

    for (int t = 0; t < TT; ++t) {
        mm_f16<<<mmgrid, 256, 0, stream>>>(Af, Bf, St);
        dense_gates<<<RTOT / 64, 256, 0, stream>>>(St, Wfeg, beg, hf, zf, Bf);
        mm_f16<<<mmgrid, 256, 0, stream>>>(Af, Bf, St);
        dense_cand<<<RTOT / 64, 256, 0, stream>>>(St, Wfeu, beu, zf, hf, Bf,
                                                  (t + 1 < TT) ? x : nullptr, t + 1,
                                                  nullptr, nullptr, nullptr, 0, hor, 0);
    }
    for (int t = 0; t < hor; ++t) {
        mm_f16<<<mmgrid, 256, 0, stream>>>(Af, Bf, St);
        dense_gates<<<RTOT / 64, 256, 0, stream>>>(St, Wfdg, bdg, hf, zf, Bf);
        mm_f16<<<mmgrid, 256, 0, stream>>>(Af, Bf, St);
        dense_cand<<<RTOT / 64, 256, 0, stream>>>(St, Wfdu, bdu, zf, hf, Bf,
                                                  nullptr, 0,
                                                  Wp, bp, out, t, hor, 1);
    }
}

// Round 7
// 672.211 us; speedup vs baseline: 1.6021x; 1.6021x over previous
//
#include <hip/hip_runtime.h>
#include <hip/hip_bf16.h>
#include <math.h>

// Problem constants
#define BB 32
#define TT 12
#define NN 512
#define HH 64
#define DIN 65
#define MSUB 96        // ROWS/16 (ROWS = 3*512)
#define RTOT 16384     // BB*NN dense rows
#define PSUB 5         // 80 padded cols per batch
#define STGBUF 17408   // f16 per staging buffer (34 subtiles x 512)

typedef _Float16 f16;
typedef f16 f16x8 __attribute__((ext_vector_type(8)));
typedef float f32x4 __attribute__((ext_vector_type(4)));

#define GLD_LDS16(g, l) \
    __builtin_amdgcn_global_load_lds((const __attribute__((address_space(1))) void*)(g), \
                                     (__attribute__((address_space(3))) void*)(l), 16, 0, 0)

// Bf element address: node j (K-dim), batch b, local col p in [0,80)
__device__ __forceinline__ size_t bf_addr(int j, int b, int p) {
    return ((size_t)(((j >> 5) * 32 + b) * PSUB + (p >> 4)) * 64 + ((j >> 3) & 3) * 16 + (p & 15)) * 8 + (j & 7);
}

// ---------------- convert P (f32, 1536x512 row-major) -> fragment-major f16 A ----------------
__global__ __launch_bounds__(256) void conv_a(const float* __restrict__ P, f16* __restrict__ Af) {
    int u = blockIdx.x * 256 + threadIdx.x;  // 1536*512/8 slots
    int lane = u & 63;
    int su = u >> 6;
    int ks = su / MSUB, ms = su - ks * MSUB;
    int m = ms * 16 + (lane & 15);
    int k = ks * 32 + (lane >> 4) * 8;
    const float* src = &P[(size_t)m * 512 + k];
    f16x8 v;
#pragma unroll
    for (int i = 0; i < 8; ++i) v[i] = (f16)src[i];
    *(f16x8*)&Af[(size_t)u * 8] = v;
}

// -------- convert dense weight (195 x O f32) -> K-permuted fragment pack matching in-reg S^T --
// slot = s*OS + os; lane (o_l,g); elem i: f = 2s + (i>=4), (kl,ps) = f/5,f%5,
// p = ps*16 + 4g + (i&3), k_orig = kl*65 + p; zero if f==15 or p>=65.
__global__ __launch_bounds__(256) void conv_w(const float* __restrict__ W, int O, int OS,
                                              f16* __restrict__ Wf) {
    int u = blockIdx.x * 256 + threadIdx.x;
    if (u >= 8 * OS * 64) return;
    int lane = u & 63, slot = u >> 6;
    int s = slot / OS, os = slot - s * OS;
    int o = os * 16 + (lane & 15);
    int g = lane >> 4;
    f16x8 v;
#pragma unroll
    for (int i = 0; i < 8; ++i) {
        int f = 2 * s + (i >= 4 ? 1 : 0);
        int kl = f / 5, ps = f - kl * 5;
        int p = ps * 16 + 4 * g + (i & 3);
        v[i] = (f < 15 && p < 65) ? (f16)W[(size_t)(kl * 65 + p) * O + o] : (f16)0.f;
    }
    *(f16x8*)&Wf[(size_t)u * 8] = v;
}

// ---------------- write x[b,t,:,0] into Bf p=0 col (prologue) ----------------
__global__ __launch_bounds__(256) void upd_x(const float* __restrict__ x, int t,
                                             f16* __restrict__ Bf) {
    int idx = blockIdx.x * 256 + threadIdx.x;
    if (idx >= RTOT) return;
    int b = idx >> 9, n = idx & 511;
    Bf[bf_addr(n, b, 0)] = (f16)x[((size_t)b * TT + t) * NN + n];
}

// ---------------- shared mm: S^T chunk for (batch b, node-band mb) into acc[15] ----------------
// acc[f=kl*5+ps] at lane (node_l=lane&15, g): S[kl*512+node][b, p=ps*16+4g+rI]
__device__ __forceinline__ void stage_tile(const f16* __restrict__ Af,
                                           const f16* __restrict__ BfIn,
                                           f16* __restrict__ lds,
                                           int b, int mb, int wave, int lane, int d, int it) {
#pragma unroll
    for (int qi = 0; qi < 9; ++qi) {
        int q = qi * 4 + wave;
        if (q < 34) {
            const f16* src;
            if (q < 24) {
                int ksl = q / 12, aid = q % 12;
                int msub = (aid >> 2) * 32 + mb * 4 + (aid & 3);
                src = &Af[((size_t)((it * 2 + ksl) * MSUB + msub) * 64 + lane) * 8];
            } else {
                int qb = q - 24;
                int ksl = qb / 5, ps = qb - ksl * 5;
                src = &BfIn[((size_t)(((it * 2 + ksl) * 32 + b) * PSUB + ps) * 64 + lane) * 8];
            }
            GLD_LDS16(src, &lds[d * STGBUF + q * 512 + lane * 8]);
        }
    }
}

__device__ __forceinline__ void gcn_mm(const f16* __restrict__ Af,
                                       const f16* __restrict__ BfIn,
                                       f16* __restrict__ lds,
                                       int b, int mb, int wave, int lane,
                                       f32x4 (&acc)[15]) {
    stage_tile(Af, BfIn, lds, b, mb, wave, lane, 0, 0);
#pragma unroll 1
    for (int it = 0; it < 8; ++it) {
        int d = it & 1;
        __syncthreads();
        if (it < 7) stage_tile(Af, BfIn, lds, b, mb, wave, lane, d ^ 1, it + 1);
#pragma unroll
        for (int s = 0; s < 2; ++s) {
            f16x8 bfr[5], afr[3];
#pragma unroll
            for (int ps = 0; ps < PSUB; ++ps)
                bfr[ps] = *(const f16x8*)&lds[d * STGBUF + (24 + s * 5 + ps) * 512 + lane * 8];
#pragma unroll
            for (int k = 0; k < 3; ++k)
                afr[k] = *(const f16x8*)&lds[d * STGBUF + (s * 12 + k * 4 + wave) * 512 + lane * 8];
#pragma unroll
            for (int k = 0; k < 3; ++k)
#pragma unroll
                for (int ps = 0; ps < PSUB; ++ps)
                    acc[k * 5 + ps] = __builtin_amdgcn_mfma_f32_16x16x32_f16(bfr[ps], afr[k], acc[k * 5 + ps], 0, 0, 0);
        }
    }
}

// build dense A-operand fragments from acc (K-permuted to match conv_w)
__device__ __forceinline__ void build_ad(const f32x4 (&acc)[15], f16x8 (&ad)[8]) {
#pragma unroll
    for (int s = 0; s < 8; ++s)
#pragma unroll
        for (int i = 0; i < 4; ++i) {
            ad[s][i] = (f16)acc[2 * s][i];
            ad[s][4 + i] = (s < 7) ? (f16)acc[2 * s + 1][i] : (f16)0.f;
        }
}

// ---------------- fused gates phase: mm + zr-dense + sigmoid; z->zf, r*h->BfOut; p0 copy ------
__global__ __launch_bounds__(256, 1) void fused_gates(const f16* __restrict__ Af,
                                                      const f16* __restrict__ BfIn,
                                                      f16* __restrict__ BfOut,
                                                      const f16* __restrict__ Wf,
                                                      const float* __restrict__ bias,
                                                      const float* __restrict__ hf,
                                                      float* __restrict__ zf) {
    __shared__ f16 lds[2 * STGBUF];
    int tid = threadIdx.x, wave = tid >> 6, lane = tid & 63;
    int b = blockIdx.x >> 3, mb = blockIdx.x & 7;
    f32x4 acc[15] = {};
    gcn_mm(Af, BfIn, lds, b, mb, wave, lane, acc);

    f16x8 ad[8];
    build_ad(acc, ad);

    __syncthreads();  // all waves done reading staging lds
#pragma unroll
    for (int qi = 0; qi < 16; ++qi) {
        int q = qi * 4 + wave;  // 64 W subtiles
        GLD_LDS16(&Wf[((size_t)q * 64 + lane) * 8], &lds[q * 512 + lane * 8]);
    }
    __syncthreads();

    f32x4 acc2[8] = {};
#pragma unroll
    for (int s = 0; s < 8; ++s)
#pragma unroll
        for (int os = 0; os < 8; ++os) {
            f16x8 w = *(const f16x8*)&lds[(s * 8 + os) * 512 + lane * 8];
            acc2[os] = __builtin_amdgcn_mfma_f32_16x16x32_f16(ad[s], w, acc2[os], 0, 0, 0);
        }

    int o_l = lane & 15, g = lane >> 4;
    int node0 = mb * 64 + wave * 16;
    int rf = b * 32 + mb * 4 + wave;
#pragma unroll
    for (int os = 0; os < 4; ++os) {  // z
        f32x4 v;
#pragma unroll
        for (int rI = 0; rI < 4; ++rI)
            v[rI] = 1.f / (1.f + expf(-(acc2[os][rI] + bias[os * 16 + o_l])));
        *(f32x4*)&zf[((size_t)(rf * 4 + os) * 64 + lane) * 4] = v;
    }
#pragma unroll
    for (int os = 4; os < 8; ++os) {  // r -> r*h
        int osh = os - 4;
        f32x4 hv = *(const f32x4*)&hf[((size_t)(rf * 4 + osh) * 64 + lane) * 4];
#pragma unroll
        for (int rI = 0; rI < 4; ++rI) {
            float rr = 1.f / (1.f + expf(-(acc2[os][rI] + bias[64 + osh * 16 + o_l])));
            int n = node0 + 4 * g + rI;
            BfOut[bf_addr(n, b, 1 + osh * 16 + o_l)] = (f16)(rr * hv[rI]);
        }
    }
    if (tid < 64) {  // p0 col copy (x or go)
        int n = mb * 64 + tid;
        BfOut[bf_addr(n, b, 0)] = BfIn[bf_addr(n, b, 0)];
    }
}

// -------- fused cand phase: mm + cand-dense + tanh + GRU update; h->hf,BfOut; tail x/proj -----
__global__ __launch_bounds__(256, 1) void fused_cand(const f16* __restrict__ Af,
                                                     const f16* __restrict__ BfIn,
                                                     f16* __restrict__ BfOut,
                                                     const f16* __restrict__ Wf,
                                                     const float* __restrict__ bias,
                                                     const float* __restrict__ zf,
                                                     float* __restrict__ hf,
                                                     const float* __restrict__ xnext, int tnext,
                                                     const float* __restrict__ Wp,
                                                     const float* __restrict__ bp,
                                                     float* __restrict__ outp, int t, int hor,
                                                     int mode) {
    __shared__ f16 lds[2 * STGBUF];
    int tid = threadIdx.x, wave = tid >> 6, lane = tid & 63;
    int b = blockIdx.x >> 3, mb = blockIdx.x & 7;
    f32x4 acc[15] = {};
    gcn_mm(Af, BfIn, lds, b, mb, wave, lane, acc);

    f16x8 ad[8];
    build_ad(acc, ad);

    __syncthreads();
#pragma unroll
    for (int qi = 0; qi < 8; ++qi) {
        int q = qi * 4 + wave;  // 32 W subtiles
        GLD_LDS16(&Wf[((size_t)q * 64 + lane) * 8], &lds[q * 512 + lane * 8]);
    }
    __syncthreads();

    f32x4 acc2[4] = {};
#pragma unroll
    for (int s = 0; s < 8; ++s)
#pragma unroll
        for (int os = 0; os < 4; ++os) {
            f16x8 w = *(const f16x8*)&lds[(s * 4 + os) * 512 + lane * 8];
            acc2[os] = __builtin_amdgcn_mfma_f32_16x16x32_f16(ad[s], w, acc2[os], 0, 0, 0);
        }

    int o_l = lane & 15, g = lane >> 4;
    int node0 = mb * 64 + wave * 16;
    int rf = b * 32 + mb * 4 + wave;
    float pp[4] = {0.f, 0.f, 0.f, 0.f};
#pragma unroll
    for (int os = 0; os < 4; ++os) {
        int o = os * 16 + o_l;
        float wp = mode ? Wp[o] : 0.f;
        f32x4 zv = *(const f32x4*)&zf[((size_t)(rf * 4 + os) * 64 + lane) * 4];
        f32x4 hv = *(const f32x4*)&hf[((size_t)(rf * 4 + os) * 64 + lane) * 4];
        f32x4 hn;
#pragma unroll
        for (int rI = 0; rI < 4; ++rI) {
            float hc = tanhf(acc2[os][rI] + bias[o]);
            hn[rI] = (1.f - zv[rI]) * hv[rI] + zv[rI] * hc;
            pp[rI] += hn[rI] * wp;
        }
        *(f32x4*)&hf[((size_t)(rf * 4 + os) * 64 + lane) * 4] = hn;
#pragma unroll
        for (int rI = 0; rI < 4; ++rI) {
            int n = node0 + 4 * g + rI;
            BfOut[bf_addr(n, b, 1 + o)] = (f16)hn[rI];
        }
    }
    if (mode) {  // decoder: proj + out + p0
#pragma unroll
        for (int m = 1; m < 16; m <<= 1)
#pragma unroll
            for (int rI = 0; rI < 4; ++rI) pp[rI] += __shfl_xor(pp[rI], m, 64);
        if (o_l == 0) {
#pragma unroll
            for (int rI = 0; rI < 4; ++rI) {
                int n = node0 + 4 * g + rI;
                float v = pp[rI] + bp[0];
                outp[((size_t)b * hor + t) * NN + n] = v;
                BfOut[bf_addr(n, b, 0)] = (f16)v;
            }
        }
    } else {  // encoder: next x (or 0 at seam)
        if (o_l == 0) {
#pragma unroll
            for (int rI = 0; rI < 4; ++rI) {
                int n = node0 + 4 * g + rI;
                float v = xnext ? xnext[((size_t)b * TT + tnext) * NN + n] : 0.f;
                BfOut[bf_addr(n, b, 0)] = (f16)v;
            }
        }
    }
}

extern "C" void kernel_launch(void* const* d_in, const int* in_sizes, int n_in,
                              void* d_out, int out_size, void* d_ws, size_t ws_size,
                              hipStream_t stream) {
    const float* x   = (const float*)d_in[0];
    const float* P   = (const float*)d_in[1];
    const float* Weg = (const float*)d_in[2];
    const float* beg = (const float*)d_in[3];
    const float* Weu = (const float*)d_in[4];
    const float* beu = (const float*)d_in[5];
    const float* Wdg = (const float*)d_in[6];
    const float* bdg = (const float*)d_in[7];
    const float* Wdu = (const float*)d_in[8];
    const float* bdu = (const float*)d_in[9];
    const float* Wp  = (const float*)d_in[10];
    const float* bp  = (const float*)d_in[11];
    float* out = (float*)d_out;
    int hor = out_size / (BB * NN);

    float* ws = (float*)d_ws;
    size_t off = 0;
    float* hf = ws + off; off += (size_t)RTOT * HH;                    // 4 MB
    float* zf = ws + off; off += (size_t)RTOT * HH;                    // 4 MB
    f16* BfA  = (f16*)(ws + off); off += 16 * 32 * PSUB * 64 * 8 / 2;  // 2.62 MB
    f16* BfB  = (f16*)(ws + off); off += 16 * 32 * PSUB * 64 * 8 / 2;
    f16* Af   = (f16*)(ws + off); off += (size_t)MSUB * 16 * 512 / 2;
    f16* WfGe = (f16*)(ws + off); off += 8 * 8 * 64 * 8 / 2;
    f16* WfGd = (f16*)(ws + off); off += 8 * 8 * 64 * 8 / 2;
    f16* WfCe = (f16*)(ws + off); off += 8 * 4 * 64 * 8 / 2;
    f16* WfCd = (f16*)(ws + off); off += 8 * 4 * 64 * 8 / 2;

    size_t bf_bytes = (size_t)16 * 32 * PSUB * 64 * 8 * sizeof(f16);
    hipMemsetAsync(hf, 0, (size_t)RTOT * HH * sizeof(float), stream);
    hipMemsetAsync(BfA, 0, bf_bytes, stream);
    hipMemsetAsync(BfB, 0, bf_bytes, stream);

    conv_a<<<(MSUB * 16 * 512 / 8) / 256, 256, 0, stream>>>(P, Af);
    conv_w<<<16, 256, 0, stream>>>(Weg, 128, 8, WfGe);
    conv_w<<<16, 256, 0, stream>>>(Wdg, 128, 8, WfGd);
    conv_w<<<8,  256, 0, stream>>>(Weu, 64, 4, WfCe);
    conv_w<<<8,  256, 0, stream>>>(Wdu, 64, 4, WfCd);
    upd_x<<<RTOT / 256, 256, 0, stream>>>(x, 0, BfA);

    for (int t = 0; t < TT; ++t) {
        fused_gates<<<256, 256, 0, stream>>>(Af, BfA, BfB, WfGe, beg, hf, zf);
        fused_cand<<<256, 256, 0, stream>>>(Af, BfB, BfA, WfCe, beu, zf, hf,
                                            (t + 1 < TT) ? x : nullptr, t + 1,
                                            nullptr, nullptr, nullptr, 0, hor, 0);
    }
    for (int t = 0; t < hor; ++t) {
        fused_gates<<<256, 256, 0, stream>>>(Af, BfA, BfB, WfGd, bdg, hf, zf);
        fused_cand<<<256, 256, 0, stream>>>(Af, BfB, BfA, WfCd, bdu, zf, hf,
                                            nullptr, 0,
                                            Wp, bp, out, t, hor, 1);
    }
}